// Round 2
// baseline (733.697 us; speedup 1.0000x reference)
//
#include <hip/hip_runtime.h>
#include <math.h>

// out[b] = dot(state[b], E[idx[b]]) - logsumexp_n dot(state[b], E[n])
// B=2048, D=64, N=100000, T=1.0
//
// Kernel A: one row per lane (state row fully in VGPRs = 64 regs),
// wave-uniform stream over E rows (all lanes read the same E row ->
// should scalarize to s_load / broadcast), online logsumexp in log2
// units, batched 8 items per rescale. N split into kChunks chunks;
// partial (m2, s) per (row, chunk) into workspace.
// Kernel B: reduce 128 partials per row + selected-item dot -> out.

constexpr int kD = 64;
constexpr int kChunks = 128;
constexpr float kNegBig = -3.0e38f;       // finite "-inf" avoids NaN in merges
constexpr float kLog2e  = 1.44269504088896340736f;
constexpr float kLn2    = 0.69314718055994530942f;

__global__ __launch_bounds__(256, 4) void lse_partial_kernel(
    const float* __restrict__ state,   // [B, 64]
    const float* __restrict__ emb,     // [N, 64]
    float2* __restrict__ part,         // [B, kChunks]  (m2, s)
    int N)
{
    const int wave = threadIdx.x >> 6;
    const int lane = threadIdx.x & 63;
    const int row  = (blockIdx.y * 4 + wave) * 64 + lane;
    const int chunk = blockIdx.x;
    const int csz = (N + kChunks - 1) / kChunks;
    const int n0 = chunk * csz;
    const int n1 = min(N, n0 + csz);

    // This lane's state row in registers (16 x float4 = 64 VGPRs).
    float4 rs[16];
    const float4* sp = (const float4*)(state + (size_t)row * kD);
    #pragma unroll
    for (int k = 0; k < 16; ++k) rs[k] = sp[k];

    float m = kNegBig;   // running max, log2 units
    float s = 0.0f;      // running sum of 2^(x - m)

    int n = n0;
    for (; n + 8 <= n1; n += 8) {
        float x[8];
        #pragma unroll
        for (int j = 0; j < 8; ++j) {
            // Wave-uniform address: all 64 lanes read the same E row.
            const float4* e4 = (const float4*)(emb + (size_t)(n + j) * kD);
            float x0 = 0.f, x1 = 0.f, x2 = 0.f, x3 = 0.f;
            #pragma unroll
            for (int k = 0; k < 16; ++k) {
                float4 e = e4[k];
                x0 = fmaf(rs[k].x, e.x, x0);
                x1 = fmaf(rs[k].y, e.y, x1);
                x2 = fmaf(rs[k].z, e.z, x2);
                x3 = fmaf(rs[k].w, e.w, x3);
            }
            x[j] = ((x0 + x1) + (x2 + x3)) * kLog2e;   // logit in log2 units
        }
        float mx = fmaxf(fmaxf(fmaxf(x[0], x[1]), fmaxf(x[2], x[3])),
                         fmaxf(fmaxf(x[4], x[5]), fmaxf(x[6], x[7])));
        float mn = fmaxf(m, mx);
        float acc = 0.f;
        #pragma unroll
        for (int j = 0; j < 8; ++j) acc += __builtin_amdgcn_exp2f(x[j] - mn);
        s = s * __builtin_amdgcn_exp2f(m - mn) + acc;
        m = mn;
    }
    for (; n < n1; ++n) {                 // remainder (last chunk)
        const float4* e4 = (const float4*)(emb + (size_t)n * kD);
        float x0 = 0.f, x1 = 0.f, x2 = 0.f, x3 = 0.f;
        #pragma unroll
        for (int k = 0; k < 16; ++k) {
            float4 e = e4[k];
            x0 = fmaf(rs[k].x, e.x, x0);
            x1 = fmaf(rs[k].y, e.y, x1);
            x2 = fmaf(rs[k].z, e.z, x2);
            x3 = fmaf(rs[k].w, e.w, x3);
        }
        float x = ((x0 + x1) + (x2 + x3)) * kLog2e;
        float mn = fmaxf(m, x);
        s = s * __builtin_amdgcn_exp2f(m - mn) + __builtin_amdgcn_exp2f(x - mn);
        m = mn;
    }

    part[(size_t)row * kChunks + chunk] = make_float2(m, s);
}

__global__ __launch_bounds__(256) void finalize_kernel(
    const float* __restrict__ state,   // [B, 64]
    const float* __restrict__ emb,     // [N, 64]
    const int* __restrict__ idx,       // [B]
    const float2* __restrict__ part,   // [B, kChunks]  (m2, s)
    float* __restrict__ out,           // [B]
    int N)
{
    const int wave = threadIdx.x >> 6;
    const int lane = threadIdx.x & 63;
    const int row  = blockIdx.x * 4 + wave;

    // Each lane merges its two chunk partials (kChunks = 128 = 2*64).
    const float2* pr = part + (size_t)row * kChunks;
    float2 p0 = pr[lane];
    float2 p1 = pr[lane + 64];
    float m = fmaxf(p0.x, p1.x);
    float s = p0.y * __builtin_amdgcn_exp2f(p0.x - m)
            + p1.y * __builtin_amdgcn_exp2f(p1.x - m);

    // Wave-wide (m, s) merge.
    #pragma unroll
    for (int o = 32; o; o >>= 1) {
        float om = __shfl_xor(m, o, 64);
        float os = __shfl_xor(s, o, 64);
        float mn = fmaxf(m, om);
        s = s * __builtin_amdgcn_exp2f(m - mn)
          + os * __builtin_amdgcn_exp2f(om - mn);
        m = mn;
    }
    float lse = (m + log2f(s)) * kLn2;   // back to natural log

    // Selected-item logit: lane k holds dim k.
    int id = idx[row];
    float a = state[(size_t)row * kD + lane];
    float b = emb[(size_t)id * kD + lane];
    float d = a * b;
    #pragma unroll
    for (int o = 32; o; o >>= 1) d += __shfl_xor(d, o, 64);

    if (lane == 0) out[row] = d - lse;   // T = 1.0
}

extern "C" void kernel_launch(void* const* d_in, const int* in_sizes, int n_in,
                              void* d_out, int out_size, void* d_ws, size_t ws_size,
                              hipStream_t stream) {
    const float* state = (const float*)d_in[0];       // [B, 64]
    const int*   idx   = (const int*)d_in[1];         // [B]
    const float* emb   = (const float*)d_in[2];       // [N, 64]
    float*       out   = (float*)d_out;               // [B]

    const int B = in_sizes[0] / kD;                   // 2048
    const int N = in_sizes[2] / kD;                   // 100000

    float2* part = (float2*)d_ws;                     // B * kChunks * 8B = 2 MB

    dim3 gridA(kChunks, B / (4 * 64));                // (128, 8) -> 4096 waves
    lse_partial_kernel<<<gridA, 256, 0, stream>>>(state, emb, part, N);

    finalize_kernel<<<B / 4, 256, 0, stream>>>(state, emb, idx, part, out, N);
}